// Round 4
// baseline (917.488 us; speedup 1.0000x reference)
//
#include <hip/hip_runtime.h>

// Problem constants: H=8, B=16, G=512, NQ=512, D=512, KD=VD=64, E=512, NORM=0.125
using u8 = unsigned char;
using u16 = unsigned short;
using u32 = unsigned int;
using u64 = unsigned long long;

typedef __attribute__((ext_vector_type(8))) __bf16 bf16x8;
typedef __attribute__((ext_vector_type(4))) float f32x4;
typedef __attribute__((ext_vector_type(4))) short s16x4;
typedef __attribute__((ext_vector_type(4))) __bf16 bf16x4;

#define MFMA16(A, B, C) __builtin_amdgcn_mfma_f32_16x16x32_bf16((A), (B), (C), 0, 0, 0)

union P2 { u32 u[2]; s16x4 s; bf16x4 b; };
union P4 { u32 u[4]; bf16x8 v; };

__device__ __forceinline__ u16 f2bf(float f) {
  u32 u = __builtin_bit_cast(u32, f);
  u += 0x7fffu + ((u >> 16) & 1u);   // round-to-nearest-even
  return (u16)(u >> 16);
}

// async 16B/lane global->LDS DMA. lane i lands at base + i*16.
__device__ __forceinline__ void gl_lds16(const void* g, void* l) {
  __builtin_amdgcn_global_load_lds(
      (const __attribute__((address_space(1))) void*)g,
      (__attribute__((address_space(3))) void*)l, 16, 0, 0);
}

// ---------------------------------------------------------------- prep kernels

__global__ void prep_q_k(const float* __restrict__ q, u16* __restrict__ qb) {
  int idx = blockIdx.x * 256 + threadIdx.x;          // one per 8 elems
  const float4* p = (const float4*)q + (size_t)idx * 2;
  float4 a = p[0], b = p[1];
  u32 w0 = f2bf(a.x) | ((u32)f2bf(a.y) << 16);
  u32 w1 = f2bf(a.z) | ((u32)f2bf(a.w) << 16);
  u32 w2 = f2bf(b.x) | ((u32)f2bf(b.y) << 16);
  u32 w3 = f2bf(b.z) | ((u32)f2bf(b.w) << 16);
  ((uint4*)qb)[idx] = make_uint4(w0, w1, w2, w3);
}

struct WPtrs { const float* w[12]; };

// Wbt[col][d] = W_iw[h][d][kk],  col = iw*512 + h*64 + kk  (K-major for B-fragments)
__global__ void prep_w_k(WPtrs wp, u16* __restrict__ Wbt) {
  int iw = blockIdx.x >> 3;
  int h  = blockIdx.x & 7;
  int kk = threadIdx.x & 63;
  int dd = threadIdx.x >> 6;
  const float* W = wp.w[iw];
  for (int d = dd; d < 512; d += 4) {
    float v = W[((size_t)(h * 512 + d)) * 64 + kk];      // coalesced over kk
    Wbt[((size_t)(iw * 512 + h * 64 + kk)) * 512 + d] = f2bf(v);
  }
}

// Wot[h][e][v] = W_out[h][v][e]
__global__ void prep_wout_k(const float* __restrict__ wout, u16* __restrict__ Wot) {
  int h = blockIdx.x;
  int t = threadIdx.x;
  for (int ee = 0; ee < 2; ee++) {
    int e = ee * 256 + t;
    for (int v = 0; v < 64; v++)
      Wot[((size_t)(h * 512 + e)) * 64 + v] = f2bf(wout[((size_t)(h * 64 + v)) * 512 + e]);
  }
}

// Mb[b][c][gt][q] u64 bitword: bit g8 = mask value at g = gt*64+g8.
// c0=sparse_dist[b,q,g], c1=att[b,g,q] (transposed), c2=att[b,q,g], c3=group[b,q,g]
__global__ void prep_masks_k(const int* __restrict__ att, const int* __restrict__ grp,
                             const int* __restrict__ sd, u64* __restrict__ Mb) {
  int b = blockIdx.x, c = blockIdx.y;
  int wave = threadIdx.x >> 6, lane = threadIdx.x & 63;
  if (c != 1) {
    const int* src = (c == 0) ? sd : (c == 2) ? att : grp;
    for (int task = wave; task < 4096; task += 4) {
      int q = task >> 3, gt = task & 7;
      int v = src[((size_t)(b * 512 + q)) * 512 + gt * 64 + lane];  // lane = g8, coalesced
      u64 w = __ballot(v != 0);
      if (lane == 0) Mb[((size_t)((b * 4 + c) * 8 + gt)) * 512 + q] = w;
    }
  } else {
    for (int task = wave; task < 64; task += 4) {
      int gt = task >> 3, qb8 = task & 7;
      u64 w = 0;
      for (int g8 = 0; g8 < 64; g8++) {
        int v = att[((size_t)(b * 512 + gt * 64 + g8)) * 512 + qb8 * 64 + lane];  // lane = q, coalesced
        w |= (u64)(v != 0) << g8;
      }
      Mb[((size_t)((b * 4 + 1) * 8 + gt)) * 512 + qb8 * 64 + lane] = w;
    }
  }
}

// ---------------------------------------------------------------- pass A: all 12 projections
// (unchanged from R3: DMA staging + XOR swizzle + LDS-staged epilogue)
__global__ __launch_bounds__(256) void gemm_proj_k(const u16* __restrict__ qb,
                                                   const u16* __restrict__ Wbt,
                                                   u16* __restrict__ P) {
  __shared__ __align__(16) u16 smem[17408];
  u16* As = smem;
  u16* Bs = smem + 8192;
  int t = threadIdx.x;
  int wave = t >> 6, lane = t & 63, quad = lane >> 4, l16 = lane & 15;
  int m0w = (wave >> 1) * 64, n0w = (wave & 1) * 64;
  int bm = blockIdx.x, bn = blockIdx.y;
  f32x4 acc[4][4] = {};
  int lr8 = lane >> 3;
  int lc8 = (lane & 7) ^ lr8;
  const u16* ag = qb  + ((size_t)(bm * 128 + wave * 32 + lr8)) * 512 + lc8 * 8;
  const u16* bg = Wbt + ((size_t)(bn * 128 + wave * 32 + lr8)) * 512 + lc8 * 8;
  u16* Asd = As + wave * 2048;
  u16* Bsd = Bs + wave * 2048;
  for (int k0 = 0; k0 < 512; k0 += 64) {
    __syncthreads();
#pragma unroll
    for (int j = 0; j < 4; j++) {
      gl_lds16(ag + (size_t)j * 8 * 512 + k0, Asd + j * 512);
      gl_lds16(bg + (size_t)j * 8 * 512 + k0, Bsd + j * 512);
    }
    __syncthreads();
#pragma unroll
    for (int kc = 0; kc < 2; kc++) {
      bf16x8 am[4], bnf[4];
#pragma unroll
      for (int i = 0; i < 4; i++) {
        int ca = ((kc * 4 + quad) ^ (l16 & 7)) * 8;
        am[i]  = *(const bf16x8*)&As[(m0w + i * 16 + l16) * 64 + ca];
        bnf[i] = *(const bf16x8*)&Bs[(n0w + i * 16 + l16) * 64 + ca];
      }
#pragma unroll
      for (int mt = 0; mt < 4; mt++)
#pragma unroll
        for (int nt = 0; nt < 4; nt++)
          acc[mt][nt] = MFMA16(am[mt], bnf[nt], acc[mt][nt]);
    }
  }
  int iw = bn >> 2;
  bool isV = (iw % 3) == 2;
  int b  = bm >> 2;
  int n0 = (bm & 3) * 128;
  u16 (*Cs)[136] = (u16(*)[136])smem;
  __syncthreads();
#pragma unroll
  for (int mt = 0; mt < 4; mt++)
#pragma unroll
    for (int nt = 0; nt < 4; nt++)
#pragma unroll
      for (int r = 0; r < 4; r++) {
        int rm = m0w + mt * 16 + quad * 4 + r;
        int cn = n0w + nt * 16 + l16;
        u16 v = f2bf(acc[mt][nt][r]);
        if (!isV) Cs[rm][cn] = v;
        else      Cs[cn][rm] = v;
      }
  __syncthreads();
#pragma unroll
  for (int p = 0; p < 8; p++) {
    int idx = p * 256 + t;
    int seg  = idx & 15;
    int crow = idx >> 4;
    uint4 v = *(const uint4*)&Cs[crow][seg * 8];
    if (!isV) {
      int col = seg * 8;
      int cg = col >> 6, k = col & 63;
      int h = (bn * 2 + cg) & 7;
      u16* dst = P + ((size_t)((iw * 8 + h) * 16 + b)) * 32768 + (size_t)(n0 + crow) * 64 + k;
      *(uint4*)dst = v;
    } else {
      int cg = crow >> 6, k = crow & 63;
      int h = (bn * 2 + cg) & 7;
      u16* dst = P + ((size_t)((iw * 8 + h) * 16 + b)) * 32768 + (size_t)k * 512 + n0 + seg * 8;
      *(uint4*)dst = v;
    }
  }
}

// ---------------------------------------------------------------- pass B: fused masked attention
// grid (h=8, b=16, qt=8) -> same-h blocks (sharing K/V via L2) cluster per XCD.
// S^T = K.Q^T via x32 MFMA; P^T stays in registers as a valid B-operand of the
// 16x16x16 MFMA (A = V^T from LDS). Single barrier/iter, double-buffered V DMA.
// Max-free softmax (|s| small), u64 bitmask masks, one denom scalar per lane.
__global__ __launch_bounds__(256, 4) void attn_k(const u16* __restrict__ P,
                                                 const u64* __restrict__ Mb,
                                                 u16* __restrict__ heads) {
  __shared__ __align__(16) u16 Vs[2][4096];   // [v][64g], chunk^(v&7) swizzle
  __shared__ __align__(16) u16 Os[64][72];    // epilogue transpose
  int t = threadIdx.x;
  int wave = t >> 6, lane = t & 63, quad = lane >> 4, l16 = lane & 15;
  int h = blockIdx.x, b = blockIdx.y, qt = blockIdx.z;
  int q0 = qt * 64;
  int lr8 = lane >> 3, lc8 = (lane & 7) ^ lr8;
  int myq = q0 + wave * 16 + l16;
  float lrow = 0.f;
  f32x4 O[4] = {};

  auto issueV = [&](int it) {
    int c = it >> 3, g0 = (it & 7) * 64;
    const u16* PV = P + ((size_t)((3 * c + 2) * 8 + h) * 16 + b) * 32768;  // [v][n]
    u16* dst = Vs[it & 1] + wave * 1024;
#pragma unroll
    for (int j = 0; j < 2; j++)
      gl_lds16(PV + (size_t)(wave * 16 + j * 8 + lr8) * 512 + g0 + lc8 * 8, dst + j * 512);
  };
  issueV(0);

  for (int c = 0; c < 4; c++) {
    const u16* PQ = P + ((size_t)((3 * c + 0) * 8 + h) * 16 + b) * 32768;
    const u16* PK = P + ((size_t)((3 * c + 1) * 8 + h) * 16 + b) * 32768;
    // Q B-fragments straight to VGPRs (row myq is exactly the fragment layout)
    bf16x8 qf[2];
#pragma unroll
    for (int kc = 0; kc < 2; kc++)
      qf[kc] = *(const bf16x8*)(PQ + (size_t)myq * 64 + kc * 32 + quad * 8);
    const u64* mrow_p = Mb + ((size_t)((b * 4 + c) * 8)) * 512;

    for (int gt = 0; gt < 8; gt++) {
      int it = c * 8 + gt;
      int g0 = gt * 64;
      u64 mw = mrow_p[(size_t)gt * 512 + myq];       // one bitword per lane
      __syncthreads();                               // V buf (it&1) resident
      if (it + 1 < 32) issueV(it + 1);               // prefetch during compute
      // QK^T transposed: S^T[g][q], A = K fragments from global (L2-hot)
      f32x4 S[4];
#pragma unroll
      for (int nt = 0; nt < 4; nt++) {
        bf16x8 kf0 = *(const bf16x8*)(PK + (size_t)(g0 + nt * 16 + l16) * 64 + quad * 8);
        bf16x8 kf1 = *(const bf16x8*)(PK + (size_t)(g0 + nt * 16 + l16) * 64 + 32 + quad * 8);
        f32x4 sa = {};
        sa = MFMA16(kf0, qf[0], sa);
        sa = MFMA16(kf1, qf[1], sa);
        S[nt] = sa;
      }
      // mask + exp + pack to bf16 pairs (P^T register fragments)
      u32 mlo = (u32)mw, mhi = (u32)(mw >> 32);
      u32 pk2[4][2];
#pragma unroll
      for (int nt = 0; nt < 4; nt++) {
        u32 mwsel = (nt < 2) ? mlo : mhi;
        int base = (nt & 1) * 16 + quad * 4;
        u32 ue[4];
#pragma unroll
        for (int r = 0; r < 4; r++) {
          float ex = __expf(S[nt][r] * 0.125f);      // NORM; no max needed (|s| small)
          u32 bit = (mwsel >> (base + r)) & 1u;
          ex *= (float)bit;                          // masked -> exactly 0
          lrow += ex;
          ue[r] = __builtin_bit_cast(u32, ex) + 0x8000u;  // round-half-up to bf16
        }
        pk2[nt][0] = __builtin_amdgcn_perm(ue[1], ue[0], 0x07060302);
        pk2[nt][1] = __builtin_amdgcn_perm(ue[3], ue[2], 0x07060302);
      }
      // PV: O^T += V^T . P^T
      const u16* Vb = Vs[it & 1];
#if __has_builtin(__builtin_amdgcn_mfma_f32_16x16x16bf16_1k) || __has_builtin(__builtin_amdgcn_mfma_f32_16x16x16_bf16)
#pragma unroll
      for (int nt = 0; nt < 4; nt++) {
        P2 Bf; Bf.u[0] = pk2[nt][0]; Bf.u[1] = pk2[nt][1];
#pragma unroll
        for (int vt = 0; vt < 4; vt++) {
          int col = ((2 * nt + (quad >> 1)) ^ (l16 & 7)) * 8 + (quad & 1) * 4;
          const u32* vp = (const u32*)(Vb + (vt * 16 + l16) * 64 + col);
          P2 Af; Af.u[0] = vp[0]; Af.u[1] = vp[1];
#if __has_builtin(__builtin_amdgcn_mfma_f32_16x16x16bf16_1k)
          O[vt] = __builtin_amdgcn_mfma_f32_16x16x16bf16_1k(Af.s, Bf.s, O[vt], 0, 0, 0);
#else
          O[vt] = __builtin_amdgcn_mfma_f32_16x16x16_bf16(Af.b, Bf.b, O[vt], 0, 0, 0);
#endif
        }
      }
#else
      // fallback: assemble x32 B-fragments via quad shuffles
#pragma unroll
      for (int kc2 = 0; kc2 < 2; kc2++) {
        P4 Bf;
#pragma unroll
        for (int p2 = 0; p2 < 4; p2++) {
          int qsrc = ((quad & 1) * 2 + (p2 >> 1)) * 16 + l16;
          u32 a  = (u32)__shfl((int)pk2[2 * kc2][p2 & 1], qsrc);
          u32 b2 = (u32)__shfl((int)pk2[2 * kc2 + 1][p2 & 1], qsrc);
          Bf.u[p2] = (quad >> 1) ? b2 : a;
        }
#pragma unroll
        for (int vt = 0; vt < 4; vt++) {
          int col = ((kc2 * 4 + quad) ^ (l16 & 7)) * 8;
          bf16x8 vf = *(const bf16x8*)(Vb + (vt * 16 + l16) * 64 + col);
          O[vt] = MFMA16(vf, Bf.v, O[vt]);
        }
      }
#endif
    }
  }
  // denominator: reduce across the 4 quad-groups (same q = l16 column)
  lrow += __shfl_xor(lrow, 16);
  lrow += __shfl_xor(lrow, 32);
  float inv = (lrow > 0.f) ? 1.0f / lrow : 0.f;
  __syncthreads();
#pragma unroll
  for (int vt = 0; vt < 4; vt++)
#pragma unroll
    for (int r = 0; r < 4; r++)
      Os[wave * 16 + l16][vt * 16 + quad * 4 + r] = f2bf(O[vt][r] * inv);
  __syncthreads();
#pragma unroll
  for (int p = 0; p < 2; p++) {
    int idx = p * 256 + t;
    int row = idx >> 3;
    int seg = idx & 7;
    uint4 v = *(const uint4*)&Os[row][seg * 8];
    *(uint4*)(heads + ((size_t)(h * 16 + b) * 512 + q0 + row) * 64 + seg * 8) = v;
  }
}

// ---------------------------------------------------------------- pass C: out = heads x W_out
__global__ __launch_bounds__(256) void gemm_out_k(const u16* __restrict__ heads,
                                                  const u16* __restrict__ Wot,
                                                  float* __restrict__ out) {
  __shared__ __align__(16) u16 As[4096];
  __shared__ __align__(16) u16 Bs[4096];
  int t = threadIdx.x;
  int wave = t >> 6, lane = t & 63, quad = lane >> 4, l16 = lane & 15;
  int m0 = blockIdx.x * 64, e0 = blockIdx.y * 64;
  int b = m0 >> 9, q0 = m0 & 511;
  int lr8 = lane >> 3, lc8 = (lane & 7) ^ lr8;
  f32x4 acc[4] = {};
  for (int h = 0; h < 8; h++) {
    __syncthreads();
#pragma unroll
    for (int j = 0; j < 2; j++) {
      gl_lds16(heads + ((size_t)(h * 16 + b) * 512 + q0 + wave * 16 + j * 8 + lr8) * 64 + lc8 * 8,
               As + wave * 1024 + j * 512);
      gl_lds16(Wot + ((size_t)(h * 512 + e0 + wave * 16 + j * 8 + lr8)) * 64 + lc8 * 8,
               Bs + wave * 1024 + j * 512);
    }
    __syncthreads();
#pragma unroll
    for (int kc = 0; kc < 2; kc++) {
      bf16x8 af = *(const bf16x8*)&As[(wave * 16 + l16) * 64 + ((kc * 4 + quad) ^ (l16 & 7)) * 8];
#pragma unroll
      for (int nt = 0; nt < 4; nt++) {
        bf16x8 bfr = *(const bf16x8*)&Bs[(nt * 16 + l16) * 64 + ((kc * 4 + quad) ^ (l16 & 7)) * 8];
        acc[nt] = MFMA16(af, bfr, acc[nt]);
      }
    }
  }
#pragma unroll
  for (int nt = 0; nt < 4; nt++)
#pragma unroll
    for (int r = 0; r < 4; r++)
      out[((size_t)(b * 512 + q0 + wave * 16 + quad * 4 + r)) * 512 + e0 + nt * 16 + l16] = acc[nt][r];
}

// ---------------------------------------------------------------- launch

extern "C" void kernel_launch(void* const* d_in, const int* in_sizes, int n_in,
                              void* d_out, int out_size, void* d_ws, size_t ws_size,
                              hipStream_t stream) {
  const float* q   = (const float*)d_in[0];
  const int*   att = (const int*)d_in[1];
  const int*   grp = (const int*)d_in[2];
  const int*   sd  = (const int*)d_in[3];
  WPtrs wp;
  for (int j = 0; j < 12; j++) wp.w[j] = (const float*)d_in[4 + j];
  const float* wout = (const float*)d_in[16];

  char* ws = (char*)d_ws;
  u16* qb    = (u16*)(ws + 0);            //   8,388,608
  u16* Wbt   = (u16*)(ws + 8388608);      //   6,291,456
  u16* Wot   = (u16*)(ws + 14680064);     //     524,288
  u64* Mb    = (u64*)(ws + 15204352);     //   2,097,152
  u16* P     = (u16*)(ws + 31981568);     // 100,663,296
  u16* heads = (u16*)(ws + 132644864);    //   8,388,608
  float* out = (float*)d_out;

  prep_masks_k<<<dim3(16, 4), 256, 0, stream>>>(att, grp, sd, Mb);
  prep_q_k<<<2048, 256, 0, stream>>>(q, qb);
  prep_w_k<<<96, 256, 0, stream>>>(wp, Wbt);
  prep_wout_k<<<8, 256, 0, stream>>>(wout, Wot);
  gemm_proj_k<<<dim3(64, 48), 256, 0, stream>>>(qb, Wbt, P);
  attn_k<<<dim3(8, 16, 8), 256, 0, stream>>>(P, Mb, heads);
  gemm_out_k<<<dim3(128, 8), 256, 0, stream>>>(heads, Wot, out);
}

// Round 5
// 480.052 us; speedup vs baseline: 1.9112x; 1.9112x over previous
//
#include <hip/hip_runtime.h>

// Problem constants: H=8, B=16, G=512, NQ=512, D=512, KD=VD=64, E=512, NORM=0.125
using u8 = unsigned char;
using u16 = unsigned short;
using u32 = unsigned int;
using u64 = unsigned long long;

typedef __attribute__((ext_vector_type(8))) __bf16 bf16x8;
typedef __attribute__((ext_vector_type(4))) float f32x4;
typedef __attribute__((ext_vector_type(4))) short s16x4;
typedef __attribute__((ext_vector_type(4))) __bf16 bf16x4;

#define MFMA16(A, B, C) __builtin_amdgcn_mfma_f32_16x16x32_bf16((A), (B), (C), 0, 0, 0)

union P2 { u32 u[2]; s16x4 s; bf16x4 b; };
union P4 { u32 u[4]; bf16x8 v; };

__device__ __forceinline__ u16 f2bf(float f) {
  u32 u = __builtin_bit_cast(u32, f);
  u += 0x7fffu + ((u >> 16) & 1u);   // round-to-nearest-even
  return (u16)(u >> 16);
}

// async 16B/lane global->LDS DMA. lane i lands at base + i*16.
__device__ __forceinline__ void gl_lds16(const void* g, void* l) {
  __builtin_amdgcn_global_load_lds(
      (const __attribute__((address_space(1))) void*)g,
      (__attribute__((address_space(3))) void*)l, 16, 0, 0);
}

// ---------------------------------------------------------------- prep kernels

__global__ void prep_q_k(const float* __restrict__ q, u16* __restrict__ qb) {
  int idx = blockIdx.x * 256 + threadIdx.x;          // one per 8 elems
  const float4* p = (const float4*)q + (size_t)idx * 2;
  float4 a = p[0], b = p[1];
  u32 w0 = f2bf(a.x) | ((u32)f2bf(a.y) << 16);
  u32 w1 = f2bf(a.z) | ((u32)f2bf(a.w) << 16);
  u32 w2 = f2bf(b.x) | ((u32)f2bf(b.y) << 16);
  u32 w3 = f2bf(b.z) | ((u32)f2bf(b.w) << 16);
  ((uint4*)qb)[idx] = make_uint4(w0, w1, w2, w3);
}

struct WPtrs { const float* w[12]; };

// Wbt[col][d] = W_iw[h][d][kk],  col = iw*512 + h*64 + kk  (K-major for B-fragments)
__global__ void prep_w_k(WPtrs wp, u16* __restrict__ Wbt) {
  int iw = blockIdx.x >> 3;
  int h  = blockIdx.x & 7;
  int kk = threadIdx.x & 63;
  int dd = threadIdx.x >> 6;
  const float* W = wp.w[iw];
  for (int d = dd; d < 512; d += 4) {
    float v = W[((size_t)(h * 512 + d)) * 64 + kk];      // coalesced over kk
    Wbt[((size_t)(iw * 512 + h * 64 + kk)) * 512 + d] = f2bf(v);
  }
}

// Wot[h][e][v] = W_out[h][v][e]
__global__ void prep_wout_k(const float* __restrict__ wout, u16* __restrict__ Wot) {
  int h = blockIdx.x;
  int t = threadIdx.x;
  for (int ee = 0; ee < 2; ee++) {
    int e = ee * 256 + t;
    for (int v = 0; v < 64; v++)
      Wot[((size_t)(h * 512 + e)) * 64 + v] = f2bf(wout[((size_t)(h * 64 + v)) * 512 + e]);
  }
}

// Mb[b][c][gt][q] u64 bitword: bit g8 = mask value at g = gt*64+g8.
// c0=sparse_dist[b,q,g], c1=att[b,g,q] (transposed), c2=att[b,q,g], c3=group[b,q,g]
// grid (16 b, 8 gt, 4 c) = 512 blocks, 4 waves each. [R5: was 64 blocks -> 1.9%
// occupancy, 500us. 512 blocks >= 2/CU.]
__global__ void prep_masks_k(const int* __restrict__ att, const int* __restrict__ grp,
                             const int* __restrict__ sd, u64* __restrict__ Mb) {
  int b = blockIdx.x, gt = blockIdx.y, c = blockIdx.z;
  int wave = threadIdx.x >> 6, lane = threadIdx.x & 63;
  u64* dst = Mb + ((size_t)((b * 4 + c) * 8 + gt)) * 512;
  if (c != 1) {
    const int* src = (c == 0) ? sd : (c == 2) ? att : grp;
    for (int q = wave; q < 512; q += 4) {
      int v = src[((size_t)(b * 512 + q)) * 512 + gt * 64 + lane];  // lane = g8, coalesced
      u64 w = __ballot(v != 0);
      if (lane == 0) dst[q] = w;
    }
  } else {
    for (int qb8 = wave; qb8 < 8; qb8 += 4) {
      u64 w = 0;
#pragma unroll 8
      for (int g8 = 0; g8 < 64; g8++) {
        int v = att[((size_t)(b * 512 + gt * 64 + g8)) * 512 + qb8 * 64 + lane];  // lane = q, coalesced
        w |= (u64)(v != 0) << g8;
      }
      dst[qb8 * 64 + lane] = w;
    }
  }
}

// ---------------------------------------------------------------- pass A: all 12 projections
// (unchanged from R3: DMA staging + XOR swizzle + LDS-staged epilogue)
__global__ __launch_bounds__(256) void gemm_proj_k(const u16* __restrict__ qb,
                                                   const u16* __restrict__ Wbt,
                                                   u16* __restrict__ P) {
  __shared__ __align__(16) u16 smem[17408];
  u16* As = smem;
  u16* Bs = smem + 8192;
  int t = threadIdx.x;
  int wave = t >> 6, lane = t & 63, quad = lane >> 4, l16 = lane & 15;
  int m0w = (wave >> 1) * 64, n0w = (wave & 1) * 64;
  int bm = blockIdx.x, bn = blockIdx.y;
  f32x4 acc[4][4] = {};
  int lr8 = lane >> 3;
  int lc8 = (lane & 7) ^ lr8;
  const u16* ag = qb  + ((size_t)(bm * 128 + wave * 32 + lr8)) * 512 + lc8 * 8;
  const u16* bg = Wbt + ((size_t)(bn * 128 + wave * 32 + lr8)) * 512 + lc8 * 8;
  u16* Asd = As + wave * 2048;
  u16* Bsd = Bs + wave * 2048;
  for (int k0 = 0; k0 < 512; k0 += 64) {
    __syncthreads();
#pragma unroll
    for (int j = 0; j < 4; j++) {
      gl_lds16(ag + (size_t)j * 8 * 512 + k0, Asd + j * 512);
      gl_lds16(bg + (size_t)j * 8 * 512 + k0, Bsd + j * 512);
    }
    __syncthreads();
#pragma unroll
    for (int kc = 0; kc < 2; kc++) {
      bf16x8 am[4], bnf[4];
#pragma unroll
      for (int i = 0; i < 4; i++) {
        int ca = ((kc * 4 + quad) ^ (l16 & 7)) * 8;
        am[i]  = *(const bf16x8*)&As[(m0w + i * 16 + l16) * 64 + ca];
        bnf[i] = *(const bf16x8*)&Bs[(n0w + i * 16 + l16) * 64 + ca];
      }
#pragma unroll
      for (int mt = 0; mt < 4; mt++)
#pragma unroll
        for (int nt = 0; nt < 4; nt++)
          acc[mt][nt] = MFMA16(am[mt], bnf[nt], acc[mt][nt]);
    }
  }
  int iw = bn >> 2;
  bool isV = (iw % 3) == 2;
  int b  = bm >> 2;
  int n0 = (bm & 3) * 128;
  u16 (*Cs)[136] = (u16(*)[136])smem;
  __syncthreads();
#pragma unroll
  for (int mt = 0; mt < 4; mt++)
#pragma unroll
    for (int nt = 0; nt < 4; nt++)
#pragma unroll
      for (int r = 0; r < 4; r++) {
        int rm = m0w + mt * 16 + quad * 4 + r;
        int cn = n0w + nt * 16 + l16;
        u16 v = f2bf(acc[mt][nt][r]);
        if (!isV) Cs[rm][cn] = v;
        else      Cs[cn][rm] = v;
      }
  __syncthreads();
#pragma unroll
  for (int p = 0; p < 8; p++) {
    int idx = p * 256 + t;
    int seg  = idx & 15;
    int crow = idx >> 4;
    uint4 v = *(const uint4*)&Cs[crow][seg * 8];
    if (!isV) {
      int col = seg * 8;
      int cg = col >> 6, k = col & 63;
      int h = (bn * 2 + cg) & 7;
      u16* dst = P + ((size_t)((iw * 8 + h) * 16 + b)) * 32768 + (size_t)(n0 + crow) * 64 + k;
      *(uint4*)dst = v;
    } else {
      int cg = crow >> 6, k = crow & 63;
      int h = (bn * 2 + cg) & 7;
      u16* dst = P + ((size_t)((iw * 8 + h) * 16 + b)) * 32768 + (size_t)k * 512 + n0 + seg * 8;
      *(uint4*)dst = v;
    }
  }
}

// ---------------------------------------------------------------- pass B: fused masked attention
// grid (h=8, b=16, qt=8) -> same-h blocks (sharing K/V via L2) cluster per XCD.
// S^T = K.Q^T via x32 MFMA; P^T stays in registers as a valid B-operand of the
// 16x16x16 MFMA (A = V^T from LDS). Single barrier/iter, double-buffered V DMA.
// Max-free softmax (|s| small), u64 bitmask masks, one denom scalar per lane.
__global__ __launch_bounds__(256, 4) void attn_k(const u16* __restrict__ P,
                                                 const u64* __restrict__ Mb,
                                                 u16* __restrict__ heads) {
  __shared__ __align__(16) u16 Vs[2][4096];   // [v][64g], chunk^(v&7) swizzle
  __shared__ __align__(16) u16 Os[64][72];    // epilogue transpose
  int t = threadIdx.x;
  int wave = t >> 6, lane = t & 63, quad = lane >> 4, l16 = lane & 15;
  int h = blockIdx.x, b = blockIdx.y, qt = blockIdx.z;
  int q0 = qt * 64;
  int lr8 = lane >> 3, lc8 = (lane & 7) ^ lr8;
  int myq = q0 + wave * 16 + l16;
  float lrow = 0.f;
  f32x4 O[4] = {};

  auto issueV = [&](int it) {
    int c = it >> 3, g0 = (it & 7) * 64;
    const u16* PV = P + ((size_t)((3 * c + 2) * 8 + h) * 16 + b) * 32768;  // [v][n]
    u16* dst = Vs[it & 1] + wave * 1024;
#pragma unroll
    for (int j = 0; j < 2; j++)
      gl_lds16(PV + (size_t)(wave * 16 + j * 8 + lr8) * 512 + g0 + lc8 * 8, dst + j * 512);
  };
  issueV(0);

  for (int c = 0; c < 4; c++) {
    const u16* PQ = P + ((size_t)((3 * c + 0) * 8 + h) * 16 + b) * 32768;
    const u16* PK = P + ((size_t)((3 * c + 1) * 8 + h) * 16 + b) * 32768;
    // Q B-fragments straight to VGPRs (row myq is exactly the fragment layout)
    bf16x8 qf[2];
#pragma unroll
    for (int kc = 0; kc < 2; kc++)
      qf[kc] = *(const bf16x8*)(PQ + (size_t)myq * 64 + kc * 32 + quad * 8);
    const u64* mrow_p = Mb + ((size_t)((b * 4 + c) * 8)) * 512;

    for (int gt = 0; gt < 8; gt++) {
      int it = c * 8 + gt;
      int g0 = gt * 64;
      u64 mw = mrow_p[(size_t)gt * 512 + myq];       // one bitword per lane
      __syncthreads();                               // V buf (it&1) resident
      if (it + 1 < 32) issueV(it + 1);               // prefetch during compute
      // QK^T transposed: S^T[g][q], A = K fragments from global (L2-hot)
      f32x4 S[4];
#pragma unroll
      for (int nt = 0; nt < 4; nt++) {
        bf16x8 kf0 = *(const bf16x8*)(PK + (size_t)(g0 + nt * 16 + l16) * 64 + quad * 8);
        bf16x8 kf1 = *(const bf16x8*)(PK + (size_t)(g0 + nt * 16 + l16) * 64 + 32 + quad * 8);
        f32x4 sa = {};
        sa = MFMA16(kf0, qf[0], sa);
        sa = MFMA16(kf1, qf[1], sa);
        S[nt] = sa;
      }
      // mask + exp + pack to bf16 pairs (P^T register fragments)
      u32 mlo = (u32)mw, mhi = (u32)(mw >> 32);
      u32 pk2[4][2];
#pragma unroll
      for (int nt = 0; nt < 4; nt++) {
        u32 mwsel = (nt < 2) ? mlo : mhi;
        int base = (nt & 1) * 16 + quad * 4;
        u32 ue[4];
#pragma unroll
        for (int r = 0; r < 4; r++) {
          float ex = __expf(S[nt][r] * 0.125f);      // NORM; no max needed (|s| small)
          u32 bit = (mwsel >> (base + r)) & 1u;
          ex *= (float)bit;                          // masked -> exactly 0
          lrow += ex;
          ue[r] = __builtin_bit_cast(u32, ex) + 0x8000u;  // round-half-up to bf16
        }
        pk2[nt][0] = __builtin_amdgcn_perm(ue[1], ue[0], 0x07060302);
        pk2[nt][1] = __builtin_amdgcn_perm(ue[3], ue[2], 0x07060302);
      }
      // PV: O^T += V^T . P^T
      const u16* Vb = Vs[it & 1];
#if __has_builtin(__builtin_amdgcn_mfma_f32_16x16x16bf16_1k) || __has_builtin(__builtin_amdgcn_mfma_f32_16x16x16_bf16)
#pragma unroll
      for (int nt = 0; nt < 4; nt++) {
        P2 Bf; Bf.u[0] = pk2[nt][0]; Bf.u[1] = pk2[nt][1];
#pragma unroll
        for (int vt = 0; vt < 4; vt++) {
          int col = ((2 * nt + (quad >> 1)) ^ (l16 & 7)) * 8 + (quad & 1) * 4;
          const u32* vp = (const u32*)(Vb + (vt * 16 + l16) * 64 + col);
          P2 Af; Af.u[0] = vp[0]; Af.u[1] = vp[1];
#if __has_builtin(__builtin_amdgcn_mfma_f32_16x16x16bf16_1k)
          O[vt] = __builtin_amdgcn_mfma_f32_16x16x16bf16_1k(Af.s, Bf.s, O[vt], 0, 0, 0);
#else
          O[vt] = __builtin_amdgcn_mfma_f32_16x16x16_bf16(Af.b, Bf.b, O[vt], 0, 0, 0);
#endif
        }
      }
#else
      // fallback: assemble x32 B-fragments via quad shuffles
#pragma unroll
      for (int kc2 = 0; kc2 < 2; kc2++) {
        P4 Bf;
#pragma unroll
        for (int p2 = 0; p2 < 4; p2++) {
          int qsrc = ((quad & 1) * 2 + (p2 >> 1)) * 16 + l16;
          u32 a  = (u32)__shfl((int)pk2[2 * kc2][p2 & 1], qsrc);
          u32 b2 = (u32)__shfl((int)pk2[2 * kc2 + 1][p2 & 1], qsrc);
          Bf.u[p2] = (quad >> 1) ? b2 : a;
        }
#pragma unroll
        for (int vt = 0; vt < 4; vt++) {
          int col = ((kc2 * 4 + quad) ^ (l16 & 7)) * 8;
          bf16x8 vf = *(const bf16x8*)(Vb + (vt * 16 + l16) * 64 + col);
          O[vt] = MFMA16(vf, Bf.v, O[vt]);
        }
      }
#endif
    }
  }
  // denominator: reduce across the 4 quad-groups (same q = l16 column)
  lrow += __shfl_xor(lrow, 16);
  lrow += __shfl_xor(lrow, 32);
  float inv = (lrow > 0.f) ? 1.0f / lrow : 0.f;
  __syncthreads();
#pragma unroll
  for (int vt = 0; vt < 4; vt++)
#pragma unroll
    for (int r = 0; r < 4; r++)
      Os[wave * 16 + l16][vt * 16 + quad * 4 + r] = f2bf(O[vt][r] * inv);
  __syncthreads();
#pragma unroll
  for (int p = 0; p < 2; p++) {
    int idx = p * 256 + t;
    int row = idx >> 3;
    int seg = idx & 7;
    uint4 v = *(const uint4*)&Os[row][seg * 8];
    *(uint4*)(heads + ((size_t)(h * 16 + b) * 512 + q0 + row) * 64 + seg * 8) = v;
  }
}

// ---------------------------------------------------------------- pass C: out = heads x W_out
__global__ __launch_bounds__(256) void gemm_out_k(const u16* __restrict__ heads,
                                                  const u16* __restrict__ Wot,
                                                  float* __restrict__ out) {
  __shared__ __align__(16) u16 As[4096];
  __shared__ __align__(16) u16 Bs[4096];
  int t = threadIdx.x;
  int wave = t >> 6, lane = t & 63, quad = lane >> 4, l16 = lane & 15;
  int m0 = blockIdx.x * 64, e0 = blockIdx.y * 64;
  int b = m0 >> 9, q0 = m0 & 511;
  int lr8 = lane >> 3, lc8 = (lane & 7) ^ lr8;
  f32x4 acc[4] = {};
  for (int h = 0; h < 8; h++) {
    __syncthreads();
#pragma unroll
    for (int j = 0; j < 2; j++) {
      gl_lds16(heads + ((size_t)(h * 16 + b) * 512 + q0 + wave * 16 + j * 8 + lr8) * 64 + lc8 * 8,
               As + wave * 1024 + j * 512);
      gl_lds16(Wot + ((size_t)(h * 512 + e0 + wave * 16 + j * 8 + lr8)) * 64 + lc8 * 8,
               Bs + wave * 1024 + j * 512);
    }
    __syncthreads();
#pragma unroll
    for (int kc = 0; kc < 2; kc++) {
      bf16x8 af = *(const bf16x8*)&As[(wave * 16 + l16) * 64 + ((kc * 4 + quad) ^ (l16 & 7)) * 8];
#pragma unroll
      for (int nt = 0; nt < 4; nt++) {
        bf16x8 bfr = *(const bf16x8*)&Bs[(nt * 16 + l16) * 64 + ((kc * 4 + quad) ^ (l16 & 7)) * 8];
        acc[nt] = MFMA16(af, bfr, acc[nt]);
      }
    }
  }
#pragma unroll
  for (int nt = 0; nt < 4; nt++)
#pragma unroll
    for (int r = 0; r < 4; r++)
      out[((size_t)(b * 512 + q0 + wave * 16 + quad * 4 + r)) * 512 + e0 + nt * 16 + l16] = acc[nt][r];
}

// ---------------------------------------------------------------- launch

extern "C" void kernel_launch(void* const* d_in, const int* in_sizes, int n_in,
                              void* d_out, int out_size, void* d_ws, size_t ws_size,
                              hipStream_t stream) {
  const float* q   = (const float*)d_in[0];
  const int*   att = (const int*)d_in[1];
  const int*   grp = (const int*)d_in[2];
  const int*   sd  = (const int*)d_in[3];
  WPtrs wp;
  for (int j = 0; j < 12; j++) wp.w[j] = (const float*)d_in[4 + j];
  const float* wout = (const float*)d_in[16];

  char* ws = (char*)d_ws;
  u16* qb    = (u16*)(ws + 0);            //   8,388,608
  u16* Wbt   = (u16*)(ws + 8388608);      //   6,291,456
  u16* Wot   = (u16*)(ws + 14680064);     //     524,288
  u64* Mb    = (u64*)(ws + 15204352);     //   2,097,152
  u16* P     = (u16*)(ws + 31981568);     // 100,663,296
  u16* heads = (u16*)(ws + 132644864);    //   8,388,608
  float* out = (float*)d_out;

  prep_masks_k<<<dim3(16, 8, 4), 256, 0, stream>>>(att, grp, sd, Mb);
  prep_q_k<<<2048, 256, 0, stream>>>(q, qb);
  prep_w_k<<<96, 256, 0, stream>>>(wp, Wbt);
  prep_wout_k<<<8, 256, 0, stream>>>(wout, Wot);
  gemm_proj_k<<<dim3(64, 48), 256, 0, stream>>>(qb, Wbt, P);
  attn_k<<<dim3(8, 16, 8), 256, 0, stream>>>(P, Mb, heads);
  gemm_out_k<<<dim3(128, 8), 256, 0, stream>>>(heads, Wot, out);
}

// Round 6
// 428.969 us; speedup vs baseline: 2.1388x; 1.1191x over previous
//
#include <hip/hip_runtime.h>

// Problem constants: H=8, B=16, G=512, NQ=512, D=512, KD=VD=64, E=512, NORM=0.125
using u8 = unsigned char;
using u16 = unsigned short;
using u32 = unsigned int;
using u64 = unsigned long long;

typedef __attribute__((ext_vector_type(8))) __bf16 bf16x8;
typedef __attribute__((ext_vector_type(4))) float f32x4;

#define MFMA16(A, B, C) __builtin_amdgcn_mfma_f32_16x16x32_bf16((A), (B), (C), 0, 0, 0)

__device__ __forceinline__ u16 f2bf(float f) {
  u32 u = __builtin_bit_cast(u32, f);
  u += 0x7fffu + ((u >> 16) & 1u);   // round-to-nearest-even
  return (u16)(u >> 16);
}

__device__ __forceinline__ float fexp2(float x) {
#if __has_builtin(__builtin_amdgcn_exp2f)
  return __builtin_amdgcn_exp2f(x);
#else
  return exp2f(x);
#endif
}

// async 16B/lane global->LDS DMA. lane i lands at base + i*16.
__device__ __forceinline__ void gl_lds16(const void* g, void* l) {
  __builtin_amdgcn_global_load_lds(
      (const __attribute__((address_space(1))) void*)g,
      (__attribute__((address_space(3))) void*)l, 16, 0, 0);
}

// ---------------------------------------------------------------- prep kernels

__global__ void prep_q_k(const float* __restrict__ q, u16* __restrict__ qb) {
  int idx = blockIdx.x * 256 + threadIdx.x;          // one per 8 elems
  const float4* p = (const float4*)q + (size_t)idx * 2;
  float4 a = p[0], b = p[1];
  u32 w0 = f2bf(a.x) | ((u32)f2bf(a.y) << 16);
  u32 w1 = f2bf(a.z) | ((u32)f2bf(a.w) << 16);
  u32 w2 = f2bf(b.x) | ((u32)f2bf(b.y) << 16);
  u32 w3 = f2bf(b.z) | ((u32)f2bf(b.w) << 16);
  ((uint4*)qb)[idx] = make_uint4(w0, w1, w2, w3);
}

struct WPtrs { const float* w[12]; };

// Wbt[col][d] = W_iw[h][d][kk], col = iw*512 + h*64 + kk. Q-class weights
// (iw%3==0) pre-scaled by NORM*log2(e) so attn can use raw exp2.
// grid (12 iw, 8 h, 4 d-quarter) = 384 blocks.
__global__ void prep_w_k(WPtrs wp, u16* __restrict__ Wbt) {
  int iw = blockIdx.x, h = blockIdx.y;
  int kk = threadIdx.x & 63;
  int dd = threadIdx.x >> 6;
  int d0 = blockIdx.z * 128;
  const float* W = wp.w[iw];
  float sc = (iw % 3 == 0) ? 0.18033688011f : 1.0f;   // 0.125 * log2(e)
  for (int d = d0 + dd; d < d0 + 128; d += 4)
    Wbt[((size_t)(iw * 512 + h * 64 + kk)) * 512 + d] =
        f2bf(W[((size_t)(h * 512 + d)) * 64 + kk] * sc);
}

// Wot[h][e][v] = W_out[h][v][e].  grid (8 h, 8 eb) = 64 blocks.
__global__ void prep_wout_k(const float* __restrict__ wout, u16* __restrict__ Wot) {
  int h = blockIdx.x, eb = blockIdx.y;
  int e = eb * 64 + (threadIdx.x & 63);
  int v0 = (threadIdx.x >> 6) * 16;
  for (int v = v0; v < v0 + 16; v++)
    Wot[((size_t)(h * 512 + e)) * 64 + v] = f2bf(wout[((size_t)(h * 64 + v)) * 512 + e]);
}

// Mb[b][c][gt][q] u64 bitword: bit g8 = mask value at g = gt*64+g8.
// grid (16 b, 8 gt, 4 c) = 512 blocks.
__global__ void prep_masks_k(const int* __restrict__ att, const int* __restrict__ grp,
                             const int* __restrict__ sd, u64* __restrict__ Mb) {
  int b = blockIdx.x, gt = blockIdx.y, c = blockIdx.z;
  int wave = threadIdx.x >> 6, lane = threadIdx.x & 63;
  u64* dst = Mb + ((size_t)((b * 4 + c) * 8 + gt)) * 512;
  if (c != 1) {
    const int* src = (c == 0) ? sd : (c == 2) ? att : grp;
    for (int q = wave; q < 512; q += 4) {
      int v = src[((size_t)(b * 512 + q)) * 512 + gt * 64 + lane];  // lane = g8
      u64 w = __ballot(v != 0);
      if (lane == 0) dst[q] = w;
    }
  } else {
    for (int qb8 = wave; qb8 < 8; qb8 += 4) {
      u64 w = 0;
#pragma unroll 8
      for (int g8 = 0; g8 < 64; g8++) {
        int v = att[((size_t)(b * 512 + gt * 64 + g8)) * 512 + qb8 * 64 + lane];  // lane = q
        w |= (u64)(v != 0) << g8;
      }
      dst[qb8 * 64 + lane] = w;
    }
  }
}

// ---------------------------------------------------------------- pass A: all 12 projections
// (unchanged: DMA staging + XOR swizzle + LDS-staged epilogue)
__global__ __launch_bounds__(256) void gemm_proj_k(const u16* __restrict__ qb,
                                                   const u16* __restrict__ Wbt,
                                                   u16* __restrict__ P) {
  __shared__ __align__(16) u16 smem[17408];
  u16* As = smem;
  u16* Bs = smem + 8192;
  int t = threadIdx.x;
  int wave = t >> 6, lane = t & 63, quad = lane >> 4, l16 = lane & 15;
  int m0w = (wave >> 1) * 64, n0w = (wave & 1) * 64;
  int bm = blockIdx.x, bn = blockIdx.y;
  f32x4 acc[4][4] = {};
  int lr8 = lane >> 3;
  int lc8 = (lane & 7) ^ lr8;
  const u16* ag = qb  + ((size_t)(bm * 128 + wave * 32 + lr8)) * 512 + lc8 * 8;
  const u16* bg = Wbt + ((size_t)(bn * 128 + wave * 32 + lr8)) * 512 + lc8 * 8;
  u16* Asd = As + wave * 2048;
  u16* Bsd = Bs + wave * 2048;
  for (int k0 = 0; k0 < 512; k0 += 64) {
    __syncthreads();
#pragma unroll
    for (int j = 0; j < 4; j++) {
      gl_lds16(ag + (size_t)j * 8 * 512 + k0, Asd + j * 512);
      gl_lds16(bg + (size_t)j * 8 * 512 + k0, Bsd + j * 512);
    }
    __syncthreads();
#pragma unroll
    for (int kc = 0; kc < 2; kc++) {
      bf16x8 am[4], bnf[4];
#pragma unroll
      for (int i = 0; i < 4; i++) {
        int ca = ((kc * 4 + quad) ^ (l16 & 7)) * 8;
        am[i]  = *(const bf16x8*)&As[(m0w + i * 16 + l16) * 64 + ca];
        bnf[i] = *(const bf16x8*)&Bs[(n0w + i * 16 + l16) * 64 + ca];
      }
#pragma unroll
      for (int mt = 0; mt < 4; mt++)
#pragma unroll
        for (int nt = 0; nt < 4; nt++)
          acc[mt][nt] = MFMA16(am[mt], bnf[nt], acc[mt][nt]);
    }
  }
  int iw = bn >> 2;
  bool isV = (iw % 3) == 2;
  int b  = bm >> 2;
  int n0 = (bm & 3) * 128;
  u16 (*Cs)[136] = (u16(*)[136])smem;
  __syncthreads();
#pragma unroll
  for (int mt = 0; mt < 4; mt++)
#pragma unroll
    for (int nt = 0; nt < 4; nt++)
#pragma unroll
      for (int r = 0; r < 4; r++) {
        int rm = m0w + mt * 16 + quad * 4 + r;
        int cn = n0w + nt * 16 + l16;
        u16 v = f2bf(acc[mt][nt][r]);
        if (!isV) Cs[rm][cn] = v;
        else      Cs[cn][rm] = v;
      }
  __syncthreads();
#pragma unroll
  for (int p = 0; p < 8; p++) {
    int idx = p * 256 + t;
    int seg  = idx & 15;
    int crow = idx >> 4;
    uint4 v = *(const uint4*)&Cs[crow][seg * 8];
    if (!isV) {
      int col = seg * 8;
      int cg = col >> 6, k = col & 63;
      int h = (bn * 2 + cg) & 7;
      u16* dst = P + ((size_t)((iw * 8 + h) * 16 + b)) * 32768 + (size_t)(n0 + crow) * 64 + k;
      *(uint4*)dst = v;
    } else {
      int cg = crow >> 6, k = crow & 63;
      int h = (bn * 2 + cg) & 7;
      u16* dst = P + ((size_t)((iw * 8 + h) * 16 + b)) * 32768 + (size_t)k * 512 + n0 + seg * 8;
      *(uint4*)dst = v;
    }
  }
}

// ---------------------------------------------------------------- pass B: fused masked attention
// grid (h=8, b=16, qt=4) = 512 blocks; 4 waves; each wave owns 32 q (2 m-tiles).
// BARRIER-FREE main loop: K/V have zero intra-block reuse -> fragments loaded
// straight from global (L2-hot, quad-lanes coalesce to 64B). Masks = broadcast
// u64 bitwords. Only LDS use: wave-private Ps round-trip (C-layout -> A-layout)
// for the PV x32 MFMA. Max-free softmax via exp2 (Q weights pre-scaled).
__global__ __launch_bounds__(256) void attn_k(const u16* __restrict__ P,
                                              const u64* __restrict__ Mb,
                                              u16* __restrict__ heads) {
  __shared__ __align__(16) u16 Ps[128 * 72];
  __shared__ __align__(16) u16 Os[128 * 72];
  int t = threadIdx.x;
  int wave = t >> 6, lane = t & 63, quad = lane >> 4, l16 = lane & 15;
  int h = blockIdx.x, b = blockIdx.y, qt = blockIdx.z;
  int q0 = qt * 128;
  int qw = q0 + wave * 32;
  float lrow[2][4] = {};
  f32x4 O[2][4] = {};
  u16* Psw = Ps + (size_t)(wave * 32) * 72;   // wave-private 32 rows

  for (int c = 0; c < 4; c++) {
    const u16* PQ = P + ((size_t)((3 * c + 0) * 8 + h) * 16 + b) * 32768;
    const u16* PK = P + ((size_t)((3 * c + 1) * 8 + h) * 16 + b) * 32768;
    const u16* PV = P + ((size_t)((3 * c + 2) * 8 + h) * 16 + b) * 32768;  // [v][n]
    bf16x8 qf[2][2];
#pragma unroll
    for (int m = 0; m < 2; m++)
#pragma unroll
      for (int kc = 0; kc < 2; kc++)
        qf[m][kc] = *(const bf16x8*)(PQ + (size_t)(qw + m * 16 + l16) * 64 + kc * 32 + quad * 8);
    const u64* mbp = Mb + ((size_t)(b * 4 + c) * 8) * 512;

    for (int gt = 0; gt < 8; gt++) {
      int g0 = gt * 64;
      bf16x8 kf[4][2], vf[4][2];
#pragma unroll
      for (int nt = 0; nt < 4; nt++)
#pragma unroll
        for (int kc = 0; kc < 2; kc++) {
          kf[nt][kc] = *(const bf16x8*)(PK + (size_t)(g0 + nt * 16 + l16) * 64 + kc * 32 + quad * 8);
          vf[nt][kc] = *(const bf16x8*)(PV + (size_t)(nt * 16 + l16) * 512 + g0 + kc * 32 + quad * 8);
        }
#pragma unroll
      for (int m = 0; m < 2; m++) {
        u64 mw[4];
#pragma unroll
        for (int r = 0; r < 4; r++)
          mw[r] = mbp[(size_t)gt * 512 + qw + m * 16 + quad * 4 + r];   // quad-broadcast
        f32x4 S[4];
#pragma unroll
        for (int nt = 0; nt < 4; nt++) {
          f32x4 sa = {};
          sa = MFMA16(qf[m][0], kf[nt][0], sa);
          sa = MFMA16(qf[m][1], kf[nt][1], sa);
          S[nt] = sa;
        }
#pragma unroll
        for (int nt = 0; nt < 4; nt++) {
          int sh = (nt & 1) * 16 + l16;
#pragma unroll
          for (int r = 0; r < 4; r++) {
            u32 half = (nt < 2) ? (u32)mw[r] : (u32)(mw[r] >> 32);
            float bitf = (float)((half >> sh) & 1u);
            float ex = fexp2(S[nt][r]) * bitf;          // masked -> exactly 0
            lrow[m][r] += ex;
            Psw[(size_t)(m * 16 + quad * 4 + r) * 72 + nt * 16 + l16] = f2bf(ex);
          }
        }
      }
      // PV: O += P~ . V   (A-frag from wave-private Ps; in-wave DS ordering)
#pragma unroll
      for (int m = 0; m < 2; m++)
#pragma unroll
        for (int kc = 0; kc < 2; kc++) {
          bf16x8 ap = *(const bf16x8*)&Psw[(size_t)(m * 16 + l16) * 72 + kc * 32 + quad * 8];
#pragma unroll
          for (int vt = 0; vt < 4; vt++)
            O[m][vt] = MFMA16(ap, vf[vt][kc], O[m][vt]);
        }
    }
  }
  // normalize + transpose-store (the only barrier in the kernel)
#pragma unroll
  for (int m = 0; m < 2; m++)
#pragma unroll
    for (int r = 0; r < 4; r++) {
      float l = lrow[m][r];
      l += __shfl_xor(l, 1); l += __shfl_xor(l, 2);
      l += __shfl_xor(l, 4); l += __shfl_xor(l, 8);
      float inv = (l > 0.f) ? 1.0f / l : 0.f;
#pragma unroll
      for (int vt = 0; vt < 4; vt++)
        Os[(size_t)(wave * 32 + m * 16 + quad * 4 + r) * 72 + vt * 16 + l16] = f2bf(O[m][vt][r] * inv);
    }
  __syncthreads();
#pragma unroll
  for (int i = 0; i < 4; i++) {
    int idx = i * 256 + t;
    int row = idx >> 3, seg = idx & 7;
    uint4 v = *(const uint4*)&Os[(size_t)row * 72 + seg * 8];
    *(uint4*)(heads + ((size_t)(h * 16 + b) * 512 + q0 + row) * 64 + seg * 8) = v;
  }
}

// ---------------------------------------------------------------- pass C: out = heads x W_out
__global__ __launch_bounds__(256) void gemm_out_k(const u16* __restrict__ heads,
                                                  const u16* __restrict__ Wot,
                                                  float* __restrict__ out) {
  __shared__ __align__(16) u16 As[4096];
  __shared__ __align__(16) u16 Bs[4096];
  int t = threadIdx.x;
  int wave = t >> 6, lane = t & 63, quad = lane >> 4, l16 = lane & 15;
  int m0 = blockIdx.x * 64, e0 = blockIdx.y * 64;
  int b = m0 >> 9, q0 = m0 & 511;
  int lr8 = lane >> 3, lc8 = (lane & 7) ^ lr8;
  f32x4 acc[4] = {};
  for (int h = 0; h < 8; h++) {
    __syncthreads();
#pragma unroll
    for (int j = 0; j < 2; j++) {
      gl_lds16(heads + ((size_t)(h * 16 + b) * 512 + q0 + wave * 16 + j * 8 + lr8) * 64 + lc8 * 8,
               As + wave * 1024 + j * 512);
      gl_lds16(Wot + ((size_t)(h * 512 + e0 + wave * 16 + j * 8 + lr8)) * 64 + lc8 * 8,
               Bs + wave * 1024 + j * 512);
    }
    __syncthreads();
#pragma unroll
    for (int kc = 0; kc < 2; kc++) {
      bf16x8 af = *(const bf16x8*)&As[(wave * 16 + l16) * 64 + ((kc * 4 + quad) ^ (l16 & 7)) * 8];
#pragma unroll
      for (int nt = 0; nt < 4; nt++) {
        bf16x8 bfr = *(const bf16x8*)&Bs[(nt * 16 + l16) * 64 + ((kc * 4 + quad) ^ (l16 & 7)) * 8];
        acc[nt] = MFMA16(af, bfr, acc[nt]);
      }
    }
  }
#pragma unroll
  for (int nt = 0; nt < 4; nt++)
#pragma unroll
    for (int r = 0; r < 4; r++)
      out[((size_t)(b * 512 + q0 + wave * 16 + quad * 4 + r)) * 512 + e0 + nt * 16 + l16] = acc[nt][r];
}

// ---------------------------------------------------------------- launch

extern "C" void kernel_launch(void* const* d_in, const int* in_sizes, int n_in,
                              void* d_out, int out_size, void* d_ws, size_t ws_size,
                              hipStream_t stream) {
  const float* q   = (const float*)d_in[0];
  const int*   att = (const int*)d_in[1];
  const int*   grp = (const int*)d_in[2];
  const int*   sd  = (const int*)d_in[3];
  WPtrs wp;
  for (int j = 0; j < 12; j++) wp.w[j] = (const float*)d_in[4 + j];
  const float* wout = (const float*)d_in[16];

  char* ws = (char*)d_ws;
  u16* qb    = (u16*)(ws + 0);            //   8,388,608
  u16* Wbt   = (u16*)(ws + 8388608);      //   6,291,456
  u16* Wot   = (u16*)(ws + 14680064);     //     524,288
  u64* Mb    = (u64*)(ws + 15204352);     //   2,097,152
  u16* P     = (u16*)(ws + 31981568);     // 100,663,296
  u16* heads = (u16*)(ws + 132644864);    //   8,388,608
  float* out = (float*)d_out;

  prep_masks_k<<<dim3(16, 8, 4), 256, 0, stream>>>(att, grp, sd, Mb);
  prep_q_k<<<2048, 256, 0, stream>>>(q, qb);
  prep_w_k<<<dim3(12, 8, 4), 256, 0, stream>>>(wp, Wbt);
  prep_wout_k<<<dim3(8, 8), 256, 0, stream>>>(wout, Wot);
  gemm_proj_k<<<dim3(64, 48), 256, 0, stream>>>(qb, Wbt, P);
  attn_k<<<dim3(8, 16, 4), 256, 0, stream>>>(P, Mb, heads);
  gemm_out_k<<<dim3(128, 8), 256, 0, stream>>>(heads, Wot, out);
}